// Round 4
// baseline (40.305 us; speedup 1.0000x reference)
//
#include <hip/hip_runtime.h>

#define IMG_H 4096
#define IMG_W 6144
#define BORDER_VAL 1e20f

#define ROWS 8                    // output rows per thread
#define GX 6                      // column groups (256 thr * 4 cols = 1024)
#define GY (IMG_H / ROWS)         // 512 row groups
#define NBLK (GX * GY)            // 3072 blocks
#define BAND (GY / 8)             // 64 row-groups per XCD band

// R1 structure (8 rows x 4 cols per thread, 3072 blocks) with the 20
// per-thread edge scalar loads replaced by cross-lane shuffles: lane l's
// left edge is lane l-1's c4.w, right edge is lane l+1's c4.x. Only wave
// boundary lanes (0 and 63) do a 1-lane predicated load.
__global__ __launch_bounds__(256) void erode3x3_kernel(
    const float* __restrict__ img,
    const float* __restrict__ se,
    float* __restrict__ out)
{
    const int v    = blockIdx.x;
    const int xcd  = v & 7;                  // HW round-robins blocks over XCDs
    const int slot = v >> 3;
    const int gy   = xcd * BAND + slot / GX; // contiguous row band per XCD
    const int gx   = slot - (slot / GX) * GX;

    const int j0   = (gx * 256 + (int)threadIdx.x) * 4;  // first output col
    const int r0   = gy * ROWS;                          // first output row
    const int lane = (int)threadIdx.x & 63;

    const float s00 = se[0], s01 = se[1], s02 = se[2];
    const float s10 = se[3], s11 = se[4], s12 = se[5];
    const float s20 = se[6], s21 = se[7], s22 = se[8];

    // vbuf[p][c]: input row r0 + p - 1, columns j0-1 .. j0+4  (c = 0..5)
    float vbuf[ROWS + 2][6];
    #pragma unroll
    for (int p = 0; p < ROWS + 2; ++p) {
        const int r = r0 + p - 1;
        if (r < 0 || r >= IMG_H) {           // wave-uniform branch
            #pragma unroll
            for (int c = 0; c < 6; ++c) vbuf[p][c] = BORDER_VAL;
        } else {
            const float* __restrict__ row = img + (size_t)r * IMG_W;
            const float4 c4 = *reinterpret_cast<const float4*>(row + j0);
            vbuf[p][1] = c4.x; vbuf[p][2] = c4.y;
            vbuf[p][3] = c4.z; vbuf[p][4] = c4.w;
            // Edges from neighbor lanes (ds_bpermute, no VMEM).
            float vL = __shfl_up(c4.w, 1);
            float vR = __shfl_down(c4.x, 1);
            if (lane == 0)  vL = (j0 > 0)         ? row[j0 - 1] : BORDER_VAL;
            if (lane == 63) vR = (j0 + 4 < IMG_W) ? row[j0 + 4] : BORDER_VAL;
            vbuf[p][0] = vL;
            vbuf[p][5] = vR;
        }
    }

    #pragma unroll
    for (int rr = 0; rr < ROWS; ++rr) {
        float o[4];
        #pragma unroll
        for (int k = 0; k < 4; ++k) {
            float m;
            m =          vbuf[rr + 0][k + 0] - s00;
            m = fminf(m, vbuf[rr + 0][k + 1] - s01);
            m = fminf(m, vbuf[rr + 0][k + 2] - s02);
            m = fminf(m, vbuf[rr + 1][k + 0] - s10);
            m = fminf(m, vbuf[rr + 1][k + 1] - s11);
            m = fminf(m, vbuf[rr + 1][k + 2] - s12);
            m = fminf(m, vbuf[rr + 2][k + 0] - s20);
            m = fminf(m, vbuf[rr + 2][k + 1] - s21);
            m = fminf(m, vbuf[rr + 2][k + 2] - s22);
            o[k] = m;
        }
        float4* dst = reinterpret_cast<float4*>(out + (size_t)(r0 + rr) * IMG_W + j0);
        *dst = make_float4(o[0], o[1], o[2], o[3]);
    }
}

extern "C" void kernel_launch(void* const* d_in, const int* in_sizes, int n_in,
                              void* d_out, int out_size, void* d_ws, size_t ws_size,
                              hipStream_t stream)
{
    const float* img = (const float*)d_in[0];
    const float* se  = (const float*)d_in[1];
    float* out       = (float*)d_out;

    dim3 block(256, 1, 1);
    dim3 grid(NBLK, 1, 1);
    erode3x3_kernel<<<grid, block, 0, stream>>>(img, se, out);
}

// Round 5
// 37.246 us; speedup vs baseline: 1.0821x; 1.0821x over previous
//
#include <hip/hip_runtime.h>

#define IMG_H 4096
#define IMG_W 6144
#define BORDER_VAL 1e20f

#define ROWS 8                    // output rows per thread
#define GX 6                      // column groups (256 thr * 4 cols = 1024)
#define GY (IMG_H / ROWS)         // 512 row groups
#define NBLK (GX * GY)            // 3072 blocks
#define BAND (GY / 8)             // 64 row-groups per XCD band

typedef float v4fu __attribute__((ext_vector_type(4), aligned(4)));
typedef float v2fu __attribute__((ext_vector_type(2), aligned(4)));

// R1 structure (8 rows x 4 cols per thread, 3072 blocks). The 6-float
// input window j0-1..j0+4 is contiguous: load it as one unaligned dwordx4
// (at j0-1) + one dwordx2 (at j0+3) instead of aligned dwordx4 + 2 edge
// scalars. 20 load instrs/thread vs 30, ~26 line-touches per wave-row vs
// ~49, and all loads stay independent (no shuffle dependency chains).
__global__ __launch_bounds__(256) void erode3x3_kernel(
    const float* __restrict__ img,
    const float* __restrict__ se,
    float* __restrict__ out)
{
    const int v    = blockIdx.x;
    const int xcd  = v & 7;                  // HW round-robins blocks over XCDs
    const int slot = v >> 3;
    const int gy   = xcd * BAND + slot / GX; // contiguous row band per XCD
    const int gx   = slot - (slot / GX) * GX;

    const int j0 = (gx * 256 + (int)threadIdx.x) * 4;  // first output col
    const int r0 = gy * ROWS;                          // first output row

    const float s00 = se[0], s01 = se[1], s02 = se[2];
    const float s10 = se[3], s11 = se[4], s12 = se[5];
    const float s20 = se[6], s21 = se[7], s22 = se[8];

    // vbuf[p][c]: input row r0 + p - 1, columns j0-1 .. j0+4  (c = 0..5)
    float vbuf[ROWS + 2][6];
    #pragma unroll
    for (int p = 0; p < ROWS + 2; ++p) {
        const int r = r0 + p - 1;
        if (r < 0 || r >= IMG_H) {           // wave-uniform branch
            #pragma unroll
            for (int c = 0; c < 6; ++c) vbuf[p][c] = BORDER_VAL;
        } else {
            const float* __restrict__ row = img + (size_t)r * IMG_W;
            if (j0 > 0) {                    // 1 divergent lane only at image edge
                const v4fu a = *reinterpret_cast<const v4fu*>(row + j0 - 1);
                vbuf[p][0] = a.x; vbuf[p][1] = a.y;
                vbuf[p][2] = a.z; vbuf[p][3] = a.w;
            } else {
                const v4fu a = *reinterpret_cast<const v4fu*>(row);
                vbuf[p][0] = BORDER_VAL; vbuf[p][1] = a.x;
                vbuf[p][2] = a.y;        vbuf[p][3] = a.z;
            }
            if (j0 + 4 < IMG_W) {
                const v2fu b = *reinterpret_cast<const v2fu*>(row + j0 + 3);
                vbuf[p][4] = b.x; vbuf[p][5] = b.y;
            } else {                         // last column group only
                vbuf[p][4] = row[j0 + 3]; vbuf[p][5] = BORDER_VAL;
            }
        }
    }

    #pragma unroll
    for (int rr = 0; rr < ROWS; ++rr) {
        float o[4];
        #pragma unroll
        for (int k = 0; k < 4; ++k) {
            float m;
            m =          vbuf[rr + 0][k + 0] - s00;
            m = fminf(m, vbuf[rr + 0][k + 1] - s01);
            m = fminf(m, vbuf[rr + 0][k + 2] - s02);
            m = fminf(m, vbuf[rr + 1][k + 0] - s10);
            m = fminf(m, vbuf[rr + 1][k + 1] - s11);
            m = fminf(m, vbuf[rr + 1][k + 2] - s12);
            m = fminf(m, vbuf[rr + 2][k + 0] - s20);
            m = fminf(m, vbuf[rr + 2][k + 1] - s21);
            m = fminf(m, vbuf[rr + 2][k + 2] - s22);
            o[k] = m;
        }
        float4* dst = reinterpret_cast<float4*>(out + (size_t)(r0 + rr) * IMG_W + j0);
        *dst = make_float4(o[0], o[1], o[2], o[3]);
    }
}

extern "C" void kernel_launch(void* const* d_in, const int* in_sizes, int n_in,
                              void* d_out, int out_size, void* d_ws, size_t ws_size,
                              hipStream_t stream)
{
    const float* img = (const float*)d_in[0];
    const float* se  = (const float*)d_in[1];
    float* out       = (float*)d_out;

    dim3 block(256, 1, 1);
    dim3 grid(NBLK, 1, 1);
    erode3x3_kernel<<<grid, block, 0, stream>>>(img, se, out);
}

// Round 6
// 34.031 us; speedup vs baseline: 1.1844x; 1.0945x over previous
//
#include <hip/hip_runtime.h>

#define IMG_H 4096
#define IMG_W 6144
#define BORDER_VAL 1e20f

#define ROWS 8                    // output rows per thread
#define GX 6                      // column groups (256 thr * 4 cols = 1024)
#define GY (IMG_H / ROWS)         // 512 row groups
#define NBLK (GX * GY)            // 3072 blocks
#define BAND (GY / 8)             // 64 row-groups per XCD band

typedef float v4f __attribute__((ext_vector_type(4)));

// R1 structure (best so far, 35.1 us): 8 rows x 4 cols per thread, 3072
// blocks, aligned dwordx4 + 2 independent edge scalar loads per row,
// XCD band swizzle. Sole change vs R1: nontemporal output stores so the
// once-written output streams past L2/L3 instead of evicting the input.
__global__ __launch_bounds__(256) void erode3x3_kernel(
    const float* __restrict__ img,
    const float* __restrict__ se,
    float* __restrict__ out)
{
    const int v    = blockIdx.x;
    const int xcd  = v & 7;                  // HW round-robins blocks over XCDs
    const int slot = v >> 3;
    const int gy   = xcd * BAND + slot / GX; // contiguous row band per XCD
    const int gx   = slot - (slot / GX) * GX;

    const int j0 = (gx * 256 + (int)threadIdx.x) * 4;  // first output col
    const int r0 = gy * ROWS;                          // first output row

    const float s00 = se[0], s01 = se[1], s02 = se[2];
    const float s10 = se[3], s11 = se[4], s12 = se[5];
    const float s20 = se[6], s21 = se[7], s22 = se[8];

    // vbuf[p][c]: input row r0 + p - 1, columns j0-1 .. j0+4  (c = 0..5)
    float vbuf[ROWS + 2][6];
    #pragma unroll
    for (int p = 0; p < ROWS + 2; ++p) {
        const int r = r0 + p - 1;
        if (r < 0 || r >= IMG_H) {           // wave-uniform branch
            #pragma unroll
            for (int c = 0; c < 6; ++c) vbuf[p][c] = BORDER_VAL;
        } else {
            const float* __restrict__ row = img + (size_t)r * IMG_W;
            const float4 c4 = *reinterpret_cast<const float4*>(row + j0);
            vbuf[p][1] = c4.x; vbuf[p][2] = c4.y;
            vbuf[p][3] = c4.z; vbuf[p][4] = c4.w;
            vbuf[p][0] = (j0 > 0)         ? row[j0 - 1] : BORDER_VAL;
            vbuf[p][5] = (j0 + 4 < IMG_W) ? row[j0 + 4] : BORDER_VAL;
        }
    }

    #pragma unroll
    for (int rr = 0; rr < ROWS; ++rr) {
        float o[4];
        #pragma unroll
        for (int k = 0; k < 4; ++k) {
            float m;
            m =          vbuf[rr + 0][k + 0] - s00;
            m = fminf(m, vbuf[rr + 0][k + 1] - s01);
            m = fminf(m, vbuf[rr + 0][k + 2] - s02);
            m = fminf(m, vbuf[rr + 1][k + 0] - s10);
            m = fminf(m, vbuf[rr + 1][k + 1] - s11);
            m = fminf(m, vbuf[rr + 1][k + 2] - s12);
            m = fminf(m, vbuf[rr + 2][k + 0] - s20);
            m = fminf(m, vbuf[rr + 2][k + 1] - s21);
            m = fminf(m, vbuf[rr + 2][k + 2] - s22);
            o[k] = m;
        }
        v4f o4; o4.x = o[0]; o4.y = o[1]; o4.z = o[2]; o4.w = o[3];
        __builtin_nontemporal_store(
            o4, reinterpret_cast<v4f*>(out + (size_t)(r0 + rr) * IMG_W + j0));
    }
}

extern "C" void kernel_launch(void* const* d_in, const int* in_sizes, int n_in,
                              void* d_out, int out_size, void* d_ws, size_t ws_size,
                              hipStream_t stream)
{
    const float* img = (const float*)d_in[0];
    const float* se  = (const float*)d_in[1];
    float* out       = (float*)d_out;

    dim3 block(256, 1, 1);
    dim3 grid(NBLK, 1, 1);
    erode3x3_kernel<<<grid, block, 0, stream>>>(img, se, out);
}